// Round 8
// baseline (227.377 us; speedup 1.0000x reference)
//
#include <hip/hip_runtime.h>
#include <stdint.h>

// GCN 2-layer: out = drop(relu(A_hat * (drop(relu((A_hat*X)*W1+b1)) * W2) + b2))
// v9: k_gemm12 occupancy fix: 48KB LDS (single-buffer K64 W-tile + sH), 512 thr,
//     2 blocks/CU co-resident, m97-style 2-barrier phases. A/H frags in regs.

#define C_IN 256
#define C_HID 512
#define C_OUT 256

typedef unsigned short ushort_t;
typedef __bf16 bf16x8 __attribute__((ext_vector_type(8)));
typedef float floatx4 __attribute__((ext_vector_type(4)));

typedef __attribute__((address_space(1))) const void g1_void;
typedef __attribute__((address_space(3))) void l3_void;

__device__ __forceinline__ void gll16(const ushort_t* g, ushort_t* l) {
  __builtin_amdgcn_global_load_lds((g1_void*)g, (l3_void*)l, 16, 0, 0);
}

// ---------------- Threefry-2x32 (matches JAX) ----------------
__host__ __device__ __forceinline__ void tf_rounds(unsigned& x0, unsigned& x1,
                                                   unsigned k0, unsigned k1) {
  unsigned k2 = k0 ^ k1 ^ 0x1BD11BDAu;
#define ROT(r) { x0 += x1; x1 = (x1 << r) | (x1 >> (32 - r)); x1 ^= x0; }
  x0 += k0; x1 += k1;
  ROT(13) ROT(15) ROT(26) ROT(6)
  x0 += k1; x1 += k2 + 1u;
  ROT(17) ROT(29) ROT(16) ROT(24)
  x0 += k2; x1 += k0 + 2u;
  ROT(13) ROT(15) ROT(26) ROT(6)
  x0 += k0; x1 += k1 + 3u;
  ROT(17) ROT(29) ROT(16) ROT(24)
  x0 += k1; x1 += k2 + 4u;
  ROT(13) ROT(15) ROT(26) ROT(6)
  x0 += k2; x1 += k0 + 5u;
#undef ROT
}

__device__ __forceinline__ float drop_scale(unsigned j, unsigned k0, unsigned k1) {
  unsigned x0 = 0u, x1 = j;
  tf_rounds(x0, x1, k0, k1);
  unsigned bits = x0 ^ x1;
  float u = __uint_as_float((bits >> 9) | 0x3f800000u) - 1.0f;
  return (u < 0.5f) ? 2.0f : 0.0f;
}

// bf16 helpers (RNE)
__device__ __forceinline__ ushort_t f2bf(float f) {
  unsigned u = __float_as_uint(f);
  unsigned r = (u + 0x7fffu + ((u >> 16) & 1u)) >> 16;
  return (ushort_t)r;
}
__device__ __forceinline__ float bf2f(ushort_t h) {
  return __uint_as_float(((unsigned)h) << 16);
}

// ---------------- fused setup: zero cnt | detect dtype | weight convert ----
__global__ __launch_bounds__(256) void k_setup(const unsigned* __restrict__ raw,
                                               unsigned* __restrict__ flag,
                                               int* __restrict__ cnt, int N, int NB,
                                               const float* __restrict__ W1,
                                               const float* __restrict__ W2,
                                               ushort_t* __restrict__ h1,
                                               ushort_t* __restrict__ l1,
                                               ushort_t* __restrict__ h2,
                                               ushort_t* __restrict__ l2) {
  int b = blockIdx.x, t = threadIdx.x;
  if (b < NB) {
    int i = b * 256 + t;
    if (i < N) cnt[i] = 0;
    return;
  }
  if (b == NB) {
    __shared__ unsigned sh[256];
    unsigned acc = 0;
    for (int i = 1 + 2 * t; i < 8192; i += 512) acc |= raw[i];
    sh[t] = acc;
    __syncthreads();
    for (int s = 128; s > 0; s >>= 1) {
      if (t < s) sh[t] |= sh[t + s];
      __syncthreads();
    }
    if (t == 0) *flag = (sh[0] == 0u) ? 1u : 0u;  // 1 => int64
    return;
  }
  int idx = (b - NB - 1) * 256 + t;
  const int S1 = C_IN * C_HID;
  if (idx >= S1 + C_HID * C_OUT) return;
  const float* W; ushort_t *hi, *lo; int K, Nn, li;
  if (idx < S1) { W = W1; hi = h1; lo = l1; K = C_IN; Nn = C_HID; li = idx; }
  else { W = W2; hi = h2; lo = l2; K = C_HID; Nn = C_OUT; li = idx - S1; }
  int k = li / Nn, n = li - k * Nn;
  float v = W[li];
  ushort_t h = f2bf(v);
  hi[(size_t)n * K + k] = h;
  lo[(size_t)n * K + k] = f2bf(v - bf2f(h));
}

// dst-degree histogram straight from raw edges (cnt pre-zeroed)
__global__ __launch_bounds__(256) void k_hist(const void* __restrict__ raw,
                                              const unsigned* __restrict__ flag,
                                              int* __restrict__ cnt, int E) {
  int e = blockIdx.x * 256 + threadIdx.x;
  if (e >= E) return;
  int d;
  if (*flag) d = (int)((const long long*)raw)[E + e];
  else       d = ((const int*)raw)[E + e];
  atomicAdd(&cnt[d], 1);
}

// ---------------- single-block scan: 16 waves, shfl-based ----------------
__global__ __launch_bounds__(1024) void k_scan(const int* __restrict__ cnt,
                                               int* __restrict__ roff,
                                               int* __restrict__ cursor,
                                               float* __restrict__ dinv,
                                               int n, int E) {
  __shared__ int wsum[16];
  __shared__ int sbase;
  int t = threadIdx.x;
  int lane = t & 63, w = t >> 6;
  if (t == 0) sbase = 0;
  __syncthreads();
  for (int c0 = 0; c0 < n; c0 += 1024) {
    int i = c0 + t;
    int v = (i < n) ? cnt[i] : 0;
    int sc = v;
#pragma unroll
    for (int d = 1; d < 64; d <<= 1) {
      int u = __shfl_up(sc, d);
      if (lane >= d) sc += u;
    }
    if (lane == 63) wsum[w] = sc;
    __syncthreads();
    int wpre = 0;
#pragma unroll
    for (int k = 0; k < 16; ++k) wpre += (k < w) ? wsum[k] : 0;
    int base = sbase;
    if (i < n) {
      int excl = base + wpre + sc - v;
      roff[i] = excl;
      cursor[i] = excl;
      dinv[i] = rsqrtf((float)(v + 1));
    }
    __syncthreads();
    if (t == 1023) sbase = base + wpre + sc;
    __syncthreads();
  }
  if (t == 0) roff[n] = E;
}

__global__ __launch_bounds__(256) void k_scatter(const void* __restrict__ raw,
                                                 const unsigned* __restrict__ flag,
                                                 int* __restrict__ cursor,
                                                 int* __restrict__ csr, int E) {
  int e = blockIdx.x * 256 + threadIdx.x;
  if (e >= E) return;
  int s, d;
  if (*flag) {
    s = (int)((const long long*)raw)[e];
    d = (int)((const long long*)raw)[E + e];
  } else {
    s = ((const int*)raw)[e];
    d = ((const int*)raw)[E + e];
  }
  int slot = atomicAdd(&cursor[d], 1);
  csr[slot] = s;
}

// ---------------- gather: 4 nodes/block, csr-prefetch dbuf, unroll-8 --------
template <int EPI, int PRE>
__global__ __launch_bounds__(256) void k_gather4(const int* __restrict__ roff,
                                                 const int* __restrict__ csr,
                                                 const float* __restrict__ dinv,
                                                 const float* __restrict__ x,
                                                 const float* __restrict__ bias,
                                                 void* __restrict__ o1,
                                                 void* __restrict__ o2,
                                                 unsigned dk0, unsigned dk1) {
  int g = threadIdx.x >> 6;
  int tg = threadIdx.x & 63;
  int node = blockIdx.x * 4 + g;
  float dd = dinv[node];
  const float4* xr = (const float4*)x;
  float4 v = xr[(size_t)node * 64 + tg];
  float4 acc;
  if (PRE) acc = v;
  else acc = make_float4(dd * v.x, dd * v.y, dd * v.z, dd * v.w);
  int p = roff[node], end = roff[node + 1];
  int s[8];
  bool have = (p + 8 <= end);
  if (have) {
#pragma unroll
    for (int q = 0; q < 8; ++q) s[q] = csr[p + q];
  }
  while (have) {
    int sn[8];
    bool haven = (p + 16 <= end);
    if (haven) {
#pragma unroll
      for (int q = 0; q < 8; ++q) sn[q] = csr[p + 8 + q];
    }
    float4 r[8];
#pragma unroll
    for (int q = 0; q < 8; ++q) r[q] = xr[(size_t)s[q] * 64 + tg];
    if (PRE) {
#pragma unroll
      for (int q = 0; q < 8; ++q) {
        acc.x += r[q].x; acc.y += r[q].y; acc.z += r[q].z; acc.w += r[q].w;
      }
    } else {
      float w[8];
#pragma unroll
      for (int q = 0; q < 8; ++q) w[q] = dinv[s[q]];
#pragma unroll
      for (int q = 0; q < 8; ++q) {
        acc.x += w[q] * r[q].x; acc.y += w[q] * r[q].y;
        acc.z += w[q] * r[q].z; acc.w += w[q] * r[q].w;
      }
    }
    p += 8;
#pragma unroll
    for (int q = 0; q < 8; ++q) s[q] = sn[q];
    have = haven;
  }
  for (; p + 4 <= end; p += 4) {
    int s0 = csr[p], s1 = csr[p + 1], s2 = csr[p + 2], s3 = csr[p + 3];
    float4 a = xr[(size_t)s0 * 64 + tg];
    float4 b = xr[(size_t)s1 * 64 + tg];
    float4 c = xr[(size_t)s2 * 64 + tg];
    float4 d = xr[(size_t)s3 * 64 + tg];
    if (PRE) {
      acc.x += a.x + b.x + c.x + d.x;
      acc.y += a.y + b.y + c.y + d.y;
      acc.z += a.z + b.z + c.z + d.z;
      acc.w += a.w + b.w + c.w + d.w;
    } else {
      float w0 = dinv[s0], w1 = dinv[s1], w2 = dinv[s2], w3 = dinv[s3];
      acc.x += w0 * a.x + w1 * b.x + w2 * c.x + w3 * d.x;
      acc.y += w0 * a.y + w1 * b.y + w2 * c.y + w3 * d.y;
      acc.z += w0 * a.z + w1 * b.z + w2 * c.z + w3 * d.z;
      acc.w += w0 * a.w + w1 * b.w + w2 * c.w + w3 * d.w;
    }
  }
  for (; p < end; ++p) {
    int s0 = csr[p];
    float4 a = xr[(size_t)s0 * 64 + tg];
    if (PRE) {
      acc.x += a.x; acc.y += a.y; acc.z += a.z; acc.w += a.w;
    } else {
      float w0 = dinv[s0];
      acc.x += w0 * a.x; acc.y += w0 * a.y; acc.z += w0 * a.z; acc.w += w0 * a.w;
    }
  }
  acc.x *= dd; acc.y *= dd; acc.z *= dd; acc.w *= dd;
  if (EPI) {
    float4 bb = ((const float4*)bias)[tg];
    acc.x = fmaxf(acc.x + bb.x, 0.0f);
    acc.y = fmaxf(acc.y + bb.y, 0.0f);
    acc.z = fmaxf(acc.z + bb.z, 0.0f);
    acc.w = fmaxf(acc.w + bb.w, 0.0f);
    unsigned jb = (unsigned)node * 256u + (unsigned)tg * 4u;
    acc.x *= drop_scale(jb + 0u, dk0, dk1);
    acc.y *= drop_scale(jb + 1u, dk0, dk1);
    acc.z *= drop_scale(jb + 2u, dk0, dk1);
    acc.w *= drop_scale(jb + 3u, dk0, dk1);
    ((float4*)o1)[(size_t)node * 64 + tg] = acc;
  } else {
    ushort_t h0 = f2bf(acc.x), h1 = f2bf(acc.y), h2 = f2bf(acc.z), h3 = f2bf(acc.w);
    ushort4 hv = make_ushort4(h0, h1, h2, h3);
    ushort4 lv = make_ushort4(f2bf(acc.x - bf2f(h0)), f2bf(acc.y - bf2f(h1)),
                              f2bf(acc.z - bf2f(h2)), f2bf(acc.w - bf2f(h3)));
    ((ushort4*)o1)[(size_t)node * 64 + tg] = hv;
    ((ushort4*)o2)[(size_t)node * 64 + tg] = lv;
  }
}

// ---------------- fused gemm1+gemm2 v3: 512 thr, 48KB LDS, 2 blocks/CU ------
// 32-row slabs, grid 313. 8 waves: wm=wave&1 (2x16 rows), wn=wave>>1 (4x32 cols).
// Single-buffered K64 W-tile (32KB) + sH (16KB). m97-style 2-barrier phases;
// co-resident blocks hide stage latency. A/H frags in regs; bias preloaded.
__global__ __launch_bounds__(512) void k_gemm12(
    const ushort_t* __restrict__ Ahi, const ushort_t* __restrict__ Alo,
    const ushort_t* __restrict__ B1h, const ushort_t* __restrict__ B1l,
    const ushort_t* __restrict__ B2h, const ushort_t* __restrict__ B2l,
    const float* __restrict__ b1, const float* __restrict__ dinv,
    float* __restrict__ hw2, int M, unsigned dk0, unsigned dk1) {
  __shared__ __attribute__((aligned(16))) ushort_t sBh[8192], sBl[8192];  // 128x64
  __shared__ __attribute__((aligned(16))) ushort_t sHh[4096], sHl[4096];  // 32x128
  const int t = threadIdx.x;
  const int lane = t & 63, wave = t >> 6;       // 8 waves
  const int wm = wave & 1, wn = wave >> 1;      // rows 2x16 / cols 4x32
  const int quad = lane >> 4, l16 = lane & 15;
  const int row0 = blockIdx.x * 32;
  const int rA = wm * 16 + l16;                 // A/H fragment row (0..31)

  // ---- prologue: A frags + bias to registers ----
  bf16x8 Ah[8], Al[8];
  {
    const int ga = min(row0 + rA, M - 1);
    const ushort_t* pa = Ahi + (size_t)ga * 256 + quad * 8;
    const ushort_t* pl = Alo + (size_t)ga * 256 + quad * 8;
#pragma unroll
    for (int k8 = 0; k8 < 8; ++k8) {
      Ah[k8] = *(const bf16x8*)(pa + k8 * 32);
      Al[k8] = *(const bf16x8*)(pl + k8 * 32);
    }
  }
  float bpre[4][2];
#pragma unroll
  for (int cb = 0; cb < 4; ++cb)
#pragma unroll
    for (int j = 0; j < 2; ++j)
      bpre[cb][j] = b1[cb * 128 + wn * 32 + j * 16 + l16];
#pragma unroll
  for (int k8 = 0; k8 < 8; ++k8)
    asm volatile("" :: "v"(Ah[k8]), "v"(Al[k8]));
#pragma unroll
  for (int cb = 0; cb < 4; ++cb)
    asm volatile("" :: "v"(bpre[cb][0]), "v"(bpre[cb][1]));

  // stage 128-row x 64-K tile (hi+lo): 16 slabs of 8 rows each; 4 gll16/wave.
  // dest linear; source k-chunk pre-swizzled ^(row&7); read XORs back.
#define STG(bh_, bl_, Kd_, colb_, kb_) {                                       \
    _Pragma("unroll")                                                          \
    for (int i_ = 0; i_ < 2; ++i_) {                                           \
      int slab_ = wave * 2 + i_;                                               \
      int row_ = slab_ * 8 + (lane >> 3);                                      \
      int kch_ = (((lane & 7) ^ (row_ & 7)) * 8);                              \
      gll16(bh_ + (size_t)(colb_ + row_) * Kd_ + (kb_) + kch_,                 \
            &sBh[slab_ * 512]);                                                \
      gll16(bl_ + (size_t)(colb_ + row_) * Kd_ + (kb_) + kch_,                 \
            &sBl[slab_ * 512]);                                                \
    } }

  floatx4 acc2[2][2] = {};
  for (int cb = 0; cb < 4; ++cb) {
    floatx4 acc1[2] = {};
    // ---- gemm1: 4 phases x K64 ----
#pragma unroll
    for (int k2 = 0; k2 < 4; ++k2) {
      __syncthreads();                       // prior reads done before overwrite
      STG(B1h, B1l, 256, cb * 128, k2 * 64)
      __syncthreads();                       // staged (vmcnt drained by sync)
#pragma unroll
      for (int kk = 0; kk < 2; ++kk) {
        bf16x8 ah = Ah[k2 * 2 + kk], al = Al[k2 * 2 + kk];
#pragma unroll
        for (int j = 0; j < 2; ++j) {
          int rb = wn * 32 + j * 16 + l16;
          int ob = rb * 64 + (((kk * 4 + quad) ^ (rb & 7)) * 8);
          bf16x8 bh = *(const bf16x8*)&sBh[ob];
          bf16x8 bl = *(const bf16x8*)&sBl[ob];
          acc1[j] = __builtin_amdgcn_mfma_f32_16x16x32_bf16(ah, bh, acc1[j], 0, 0, 0);
          acc1[j] = __builtin_amdgcn_mfma_f32_16x16x32_bf16(ah, bl, acc1[j], 0, 0, 0);
          acc1[j] = __builtin_amdgcn_mfma_f32_16x16x32_bf16(al, bh, acc1[j], 0, 0, 0);
        }
      }
    }
    // ---- H1 epilogue -> sH (bias, relu, dropout, bf16 hi/lo split) ----
#pragma unroll
    for (int j = 0; j < 2; ++j) {
      int kc = wn * 32 + j * 16 + l16;    // col in tile 0..127
      int gc = cb * 128 + kc;
      float bb = bpre[cb][j];
#pragma unroll
      for (int reg = 0; reg < 4; ++reg) {
        int row = wm * 16 + quad * 4 + reg;
        float v = fmaxf(acc1[j][reg] + bb, 0.0f);
        v *= drop_scale((unsigned)(row0 + row) * 512u + (unsigned)gc, dk0, dk1);
        ushort_t h = f2bf(v);
        int idx = row * 128 + (((kc >> 3) ^ (row & 7)) * 8) + (kc & 7);
        sHh[idx] = h;
        sHl[idx] = f2bf(v - bf2f(h));
      }
    }
    __syncthreads();                        // sH complete
    // H fragments to registers (4 k-chunks x hi/lo)
    bf16x8 hh[4], hl[4];
#pragma unroll
    for (int kc2 = 0; kc2 < 4; ++kc2) {
      int oh = rA * 128 + (((kc2 * 4 + quad) ^ (rA & 7)) * 8);
      hh[kc2] = *(const bf16x8*)&sHh[oh];
      hl[kc2] = *(const bf16x8*)&sHl[oh];
    }
    // ---- gemm2: 4 phases (2 col-phases x 2 K64-steps) ----
#pragma unroll
    for (int s2 = 0; s2 < 4; ++s2) {
      const int ph = s2 >> 1, kk2 = s2 & 1;
      __syncthreads();
      STG(B2h, B2l, 512, ph * 128, cb * 128 + kk2 * 64)
      __syncthreads();
#pragma unroll
      for (int kk = 0; kk < 2; ++kk) {
        bf16x8 ah = hh[kk2 * 2 + kk], al = hl[kk2 * 2 + kk];
#pragma unroll
        for (int j = 0; j < 2; ++j) {
          int rb = wn * 32 + j * 16 + l16;
          int ob = rb * 64 + (((kk * 4 + quad) ^ (rb & 7)) * 8);
          bf16x8 bh = *(const bf16x8*)&sBh[ob];
          bf16x8 bl = *(const bf16x8*)&sBl[ob];
          acc2[ph][j] = __builtin_amdgcn_mfma_f32_16x16x32_bf16(ah, bh, acc2[ph][j], 0, 0, 0);
          acc2[ph][j] = __builtin_amdgcn_mfma_f32_16x16x32_bf16(ah, bl, acc2[ph][j], 0, 0, 0);
          acc2[ph][j] = __builtin_amdgcn_mfma_f32_16x16x32_bf16(al, bh, acc2[ph][j], 0, 0, 0);
        }
      }
    }
  }
#undef STG
  // ---- final epilogue: hw2 = acc2 * dinv[row] (row-prescale for gather2) ----
#pragma unroll
  for (int ph = 0; ph < 2; ++ph) {
#pragma unroll
    for (int j = 0; j < 2; ++j) {
      int gc = ph * 128 + wn * 32 + j * 16 + l16;
#pragma unroll
      for (int reg = 0; reg < 4; ++reg) {
        int gr = row0 + wm * 16 + quad * 4 + reg;
        if (gr < M) hw2[(size_t)gr * 256 + gc] = acc2[ph][j][reg] * dinv[gr];
      }
    }
  }
}

extern "C" void kernel_launch(void* const* d_in, const int* in_sizes, int n_in,
                              void* d_out, int out_size, void* d_ws, size_t ws_size,
                              hipStream_t stream) {
  const float* x  = (const float*)d_in[0];
  const void*  ei = d_in[1];
  const float* W1 = (const float*)d_in[2];
  const float* b1 = (const float*)d_in[3];
  const float* W2 = (const float*)d_in[4];
  const float* b2 = (const float*)d_in[5];
  float* out = (float*)d_out;

  const int N = in_sizes[0] / C_IN;   // 10000
  const int E = in_sizes[1] / 2;      // 160000
  const int NB = (N + 255) / 256;     // 40

  unsigned a0 = 0u, a1 = 0u, b0 = 0u, b1k = 1u;
  tf_rounds(a0, a1, 0u, 42u);   // dk1
  tf_rounds(b0, b1k, 0u, 42u);  // dk2

  uintptr_t base = (uintptr_t)d_ws;
  unsigned*  flag   = (unsigned*)base;
  int*       cnt    = (int*)(base + 16 * 1024);
  int*       roff   = (int*)(base + 64 * 1024);
  int*       cursor = (int*)(base + 128 * 1024);
  float*     dinv   = (float*)(base + 192 * 1024);
  int*       csr    = (int*)(base + 2u * 1024 * 1024);
  ushort_t*  Ahi    = (ushort_t*)(base + 4u  * 1024 * 1024);
  ushort_t*  Alo    = (ushort_t*)(base + 10u * 1024 * 1024);
  float*     hw2    = (float*)(base + 38u * 1024 * 1024);
  ushort_t*  W1thi  = (ushort_t*)(base + 49u * 1024 * 1024);
  ushort_t*  W1tlo  = (ushort_t*)(base + 49u * 1024 * 1024 + 512 * 1024);
  ushort_t*  W2thi  = (ushort_t*)(base + 50u * 1024 * 1024);
  ushort_t*  W2tlo  = (ushort_t*)(base + 50u * 1024 * 1024 + 512 * 1024);

  dim3 b256(256);
  const int WCB = (C_IN * C_HID + C_HID * C_OUT + 255) / 256;

  // 1. fused setup: zero cnt | detect | weight convert
  k_setup<<<dim3(NB + 1 + WCB), b256, 0, stream>>>((const unsigned*)ei, flag, cnt,
                                                   N, NB, W1, W2,
                                                   W1thi, W1tlo, W2thi, W2tlo);
  // 2. degree histogram
  k_hist<<<dim3((E + 255) / 256), b256, 0, stream>>>(ei, flag, cnt, E);
  // 3. single-block scan
  k_scan<<<dim3(1), dim3(1024), 0, stream>>>(cnt, roff, cursor, dinv, N, E);
  // 4. CSR scatter
  k_scatter<<<dim3((E + 255) / 256), b256, 0, stream>>>(ei, flag, cursor, csr, E);
  // 5. layer-1 aggregate (full-TLP gather) -> bf16 split A
  k_gather4<0, 0><<<dim3(N / 4), b256, 0, stream>>>(roff, csr, dinv, x, nullptr,
                                                    Ahi, Alo, 0u, 0u);
  // 6. fused gemm1+gemm2 -> hw2 (row-prescaled); H1 never leaves LDS
  k_gemm12<<<dim3((N + 31) / 32), dim3(512), 0, stream>>>(
      Ahi, Alo, W1thi, W1tlo, W2thi, W2tlo, b1, dinv, hw2, N, a0, a1);
  // 7. out = drop(relu(dd * (sum hw2'[nbrs] + hw2'[self]) + b2))
  k_gather4<1, 1><<<dim3(N / 4), b256, 0, stream>>>(roff, csr, dinv, hw2, b2,
                                                    out, nullptr, b0, b1k);
}

// Round 9
// 205.481 us; speedup vs baseline: 1.1066x; 1.1066x over previous
//
#include <hip/hip_runtime.h>
#include <stdint.h>

// GCN 2-layer: out = drop(relu(A_hat * (drop(relu((A_hat*X)*W1+b1)) * W2) + b2))
// v10: reassembly of measured-best components. Fused-GEMM experiments (v6-v9:
//      52/56/79us) all lost to v4's standalone pair (~21us each) -> reverted.
//      v5 preproc (4 launches, eic-free) + v5 gathers + v4 k_gemm3 verbatim.

#define C_IN 256
#define C_HID 512
#define C_OUT 256

typedef unsigned short ushort_t;
typedef __bf16 bf16x8 __attribute__((ext_vector_type(8)));
typedef float floatx4 __attribute__((ext_vector_type(4)));

typedef __attribute__((address_space(1))) const void g1_void;
typedef __attribute__((address_space(3))) void l3_void;

__device__ __forceinline__ void gll16(const ushort_t* g, ushort_t* l) {
  __builtin_amdgcn_global_load_lds((g1_void*)g, (l3_void*)l, 16, 0, 0);
}

// ---------------- Threefry-2x32 (matches JAX) ----------------
__host__ __device__ __forceinline__ void tf_rounds(unsigned& x0, unsigned& x1,
                                                   unsigned k0, unsigned k1) {
  unsigned k2 = k0 ^ k1 ^ 0x1BD11BDAu;
#define ROT(r) { x0 += x1; x1 = (x1 << r) | (x1 >> (32 - r)); x1 ^= x0; }
  x0 += k0; x1 += k1;
  ROT(13) ROT(15) ROT(26) ROT(6)
  x0 += k1; x1 += k2 + 1u;
  ROT(17) ROT(29) ROT(16) ROT(24)
  x0 += k2; x1 += k0 + 2u;
  ROT(13) ROT(15) ROT(26) ROT(6)
  x0 += k0; x1 += k1 + 3u;
  ROT(17) ROT(29) ROT(16) ROT(24)
  x0 += k1; x1 += k2 + 4u;
  ROT(13) ROT(15) ROT(26) ROT(6)
  x0 += k2; x1 += k0 + 5u;
#undef ROT
}

__device__ __forceinline__ float drop_scale(unsigned j, unsigned k0, unsigned k1) {
  unsigned x0 = 0u, x1 = j;
  tf_rounds(x0, x1, k0, k1);
  unsigned bits = x0 ^ x1;
  float u = __uint_as_float((bits >> 9) | 0x3f800000u) - 1.0f;
  return (u < 0.5f) ? 2.0f : 0.0f;
}

// bf16 helpers (RNE)
__device__ __forceinline__ ushort_t f2bf(float f) {
  unsigned u = __float_as_uint(f);
  unsigned r = (u + 0x7fffu + ((u >> 16) & 1u)) >> 16;
  return (ushort_t)r;
}
__device__ __forceinline__ float bf2f(ushort_t h) {
  return __uint_as_float(((unsigned)h) << 16);
}

// ---------------- fused setup: zero cnt | detect dtype | weight convert ----
__global__ __launch_bounds__(256) void k_setup(const unsigned* __restrict__ raw,
                                               unsigned* __restrict__ flag,
                                               int* __restrict__ cnt, int N, int NB,
                                               const float* __restrict__ W1,
                                               const float* __restrict__ W2,
                                               ushort_t* __restrict__ h1,
                                               ushort_t* __restrict__ l1,
                                               ushort_t* __restrict__ h2,
                                               ushort_t* __restrict__ l2) {
  int b = blockIdx.x, t = threadIdx.x;
  if (b < NB) {
    int i = b * 256 + t;
    if (i < N) cnt[i] = 0;
    return;
  }
  if (b == NB) {
    __shared__ unsigned sh[256];
    unsigned acc = 0;
    for (int i = 1 + 2 * t; i < 8192; i += 512) acc |= raw[i];
    sh[t] = acc;
    __syncthreads();
    for (int s = 128; s > 0; s >>= 1) {
      if (t < s) sh[t] |= sh[t + s];
      __syncthreads();
    }
    if (t == 0) *flag = (sh[0] == 0u) ? 1u : 0u;  // 1 => int64
    return;
  }
  int idx = (b - NB - 1) * 256 + t;
  const int S1 = C_IN * C_HID;
  if (idx >= S1 + C_HID * C_OUT) return;
  const float* W; ushort_t *hi, *lo; int K, Nn, li;
  if (idx < S1) { W = W1; hi = h1; lo = l1; K = C_IN; Nn = C_HID; li = idx; }
  else { W = W2; hi = h2; lo = l2; K = C_HID; Nn = C_OUT; li = idx - S1; }
  int k = li / Nn, n = li - k * Nn;
  float v = W[li];
  ushort_t h = f2bf(v);
  hi[(size_t)n * K + k] = h;
  lo[(size_t)n * K + k] = f2bf(v - bf2f(h));
}

// dst-degree histogram straight from raw edges (cnt pre-zeroed)
__global__ __launch_bounds__(256) void k_hist(const void* __restrict__ raw,
                                              const unsigned* __restrict__ flag,
                                              int* __restrict__ cnt, int E) {
  int e = blockIdx.x * 256 + threadIdx.x;
  if (e >= E) return;
  int d;
  if (*flag) d = (int)((const long long*)raw)[E + e];
  else       d = ((const int*)raw)[E + e];
  atomicAdd(&cnt[d], 1);
}

// ---------------- single-block scan: 16 waves, shfl-based ----------------
__global__ __launch_bounds__(1024) void k_scan(const int* __restrict__ cnt,
                                               int* __restrict__ roff,
                                               int* __restrict__ cursor,
                                               float* __restrict__ dinv,
                                               int n, int E) {
  __shared__ int wsum[16];
  __shared__ int sbase;
  int t = threadIdx.x;
  int lane = t & 63, w = t >> 6;
  if (t == 0) sbase = 0;
  __syncthreads();
  for (int c0 = 0; c0 < n; c0 += 1024) {
    int i = c0 + t;
    int v = (i < n) ? cnt[i] : 0;
    int sc = v;
#pragma unroll
    for (int d = 1; d < 64; d <<= 1) {
      int u = __shfl_up(sc, d);
      if (lane >= d) sc += u;
    }
    if (lane == 63) wsum[w] = sc;
    __syncthreads();
    int wpre = 0;
#pragma unroll
    for (int k = 0; k < 16; ++k) wpre += (k < w) ? wsum[k] : 0;
    int base = sbase;
    if (i < n) {
      int excl = base + wpre + sc - v;
      roff[i] = excl;
      cursor[i] = excl;
      dinv[i] = rsqrtf((float)(v + 1));
    }
    __syncthreads();
    if (t == 1023) sbase = base + wpre + sc;
    __syncthreads();
  }
  if (t == 0) roff[n] = E;
}

__global__ __launch_bounds__(256) void k_scatter(const void* __restrict__ raw,
                                                 const unsigned* __restrict__ flag,
                                                 int* __restrict__ cursor,
                                                 int* __restrict__ csr, int E) {
  int e = blockIdx.x * 256 + threadIdx.x;
  if (e >= E) return;
  int s, d;
  if (*flag) {
    s = (int)((const long long*)raw)[e];
    d = (int)((const long long*)raw)[E + e];
  } else {
    s = ((const int*)raw)[e];
    d = ((const int*)raw)[E + e];
  }
  int slot = atomicAdd(&cursor[d], 1);
  csr[slot] = s;
}

// ---------------- gather: 4 nodes/block, csr-prefetch dbuf, unroll-8 --------
template <int EPI, int PRE>
__global__ __launch_bounds__(256) void k_gather4(const int* __restrict__ roff,
                                                 const int* __restrict__ csr,
                                                 const float* __restrict__ dinv,
                                                 const float* __restrict__ x,
                                                 const float* __restrict__ bias,
                                                 void* __restrict__ o1,
                                                 void* __restrict__ o2,
                                                 unsigned dk0, unsigned dk1) {
  int g = threadIdx.x >> 6;
  int tg = threadIdx.x & 63;
  int node = blockIdx.x * 4 + g;
  float dd = dinv[node];
  const float4* xr = (const float4*)x;
  float4 v = xr[(size_t)node * 64 + tg];
  float4 acc;
  if (PRE) acc = v;
  else acc = make_float4(dd * v.x, dd * v.y, dd * v.z, dd * v.w);
  int p = roff[node], end = roff[node + 1];
  int s[8];
  bool have = (p + 8 <= end);
  if (have) {
#pragma unroll
    for (int q = 0; q < 8; ++q) s[q] = csr[p + q];
  }
  while (have) {
    int sn[8];
    bool haven = (p + 16 <= end);
    if (haven) {
#pragma unroll
      for (int q = 0; q < 8; ++q) sn[q] = csr[p + 8 + q];
    }
    float4 r[8];
#pragma unroll
    for (int q = 0; q < 8; ++q) r[q] = xr[(size_t)s[q] * 64 + tg];
    if (PRE) {
#pragma unroll
      for (int q = 0; q < 8; ++q) {
        acc.x += r[q].x; acc.y += r[q].y; acc.z += r[q].z; acc.w += r[q].w;
      }
    } else {
      float w[8];
#pragma unroll
      for (int q = 0; q < 8; ++q) w[q] = dinv[s[q]];
#pragma unroll
      for (int q = 0; q < 8; ++q) {
        acc.x += w[q] * r[q].x; acc.y += w[q] * r[q].y;
        acc.z += w[q] * r[q].z; acc.w += w[q] * r[q].w;
      }
    }
    p += 8;
#pragma unroll
    for (int q = 0; q < 8; ++q) s[q] = sn[q];
    have = haven;
  }
  for (; p + 4 <= end; p += 4) {
    int s0 = csr[p], s1 = csr[p + 1], s2 = csr[p + 2], s3 = csr[p + 3];
    float4 a = xr[(size_t)s0 * 64 + tg];
    float4 b = xr[(size_t)s1 * 64 + tg];
    float4 c = xr[(size_t)s2 * 64 + tg];
    float4 d = xr[(size_t)s3 * 64 + tg];
    if (PRE) {
      acc.x += a.x + b.x + c.x + d.x;
      acc.y += a.y + b.y + c.y + d.y;
      acc.z += a.z + b.z + c.z + d.z;
      acc.w += a.w + b.w + c.w + d.w;
    } else {
      float w0 = dinv[s0], w1 = dinv[s1], w2 = dinv[s2], w3 = dinv[s3];
      acc.x += w0 * a.x + w1 * b.x + w2 * c.x + w3 * d.x;
      acc.y += w0 * a.y + w1 * b.y + w2 * c.y + w3 * d.y;
      acc.z += w0 * a.z + w1 * b.z + w2 * c.z + w3 * d.z;
      acc.w += w0 * a.w + w1 * b.w + w2 * c.w + w3 * d.w;
    }
  }
  for (; p < end; ++p) {
    int s0 = csr[p];
    float4 a = xr[(size_t)s0 * 64 + tg];
    if (PRE) {
      acc.x += a.x; acc.y += a.y; acc.z += a.z; acc.w += a.w;
    } else {
      float w0 = dinv[s0];
      acc.x += w0 * a.x; acc.y += w0 * a.y; acc.z += w0 * a.z; acc.w += w0 * a.w;
    }
  }
  acc.x *= dd; acc.y *= dd; acc.z *= dd; acc.w *= dd;
  if (EPI) {
    float4 bb = ((const float4*)bias)[tg];
    acc.x = fmaxf(acc.x + bb.x, 0.0f);
    acc.y = fmaxf(acc.y + bb.y, 0.0f);
    acc.z = fmaxf(acc.z + bb.z, 0.0f);
    acc.w = fmaxf(acc.w + bb.w, 0.0f);
    unsigned jb = (unsigned)node * 256u + (unsigned)tg * 4u;
    acc.x *= drop_scale(jb + 0u, dk0, dk1);
    acc.y *= drop_scale(jb + 1u, dk0, dk1);
    acc.z *= drop_scale(jb + 2u, dk0, dk1);
    acc.w *= drop_scale(jb + 3u, dk0, dk1);
    ((float4*)o1)[(size_t)node * 64 + tg] = acc;
  } else {
    ushort_t h0 = f2bf(acc.x), h1 = f2bf(acc.y), h2 = f2bf(acc.z), h3 = f2bf(acc.w);
    ushort4 hv = make_ushort4(h0, h1, h2, h3);
    ushort4 lv = make_ushort4(f2bf(acc.x - bf2f(h0)), f2bf(acc.y - bf2f(h1)),
                              f2bf(acc.z - bf2f(h2)), f2bf(acc.w - bf2f(h3)));
    ((ushort4*)o1)[(size_t)node * 64 + tg] = hv;
    ((ushort4*)o2)[(size_t)node * 64 + tg] = lv;
  }
}

// ---------------- bf16x3 MFMA GEMM: 64x128 tile, dbuf gll16 + counted vmcnt -
// (v4 verbatim -- the measured-best GEMM structure this session)
template <int EPI>
__global__ __launch_bounds__(256) void k_gemm3(
    const ushort_t* __restrict__ Ahi, const ushort_t* __restrict__ Alo,
    const ushort_t* __restrict__ Bhi, const ushort_t* __restrict__ Blo,
    const float* __restrict__ bias, const float* __restrict__ dscale,
    ushort_t* __restrict__ Chi, ushort_t* __restrict__ Clo,
    float* __restrict__ Cf,
    int M, int N, int K, unsigned dk0, unsigned dk1) {
  __shared__ ushort_t sAh[2][64 * 32], sAl[2][64 * 32];
  __shared__ ushort_t sBh[2][128 * 32], sBl[2][128 * 32];
  const int t = threadIdx.x;
  const int lane = t & 63, wave = t >> 6;
  const int wm = wave & 1, wn = wave >> 1;
  const int quad = lane >> 4, l16 = lane & 15;
  const int row0 = blockIdx.y * 64, col0 = blockIdx.x * 128;
  const int srow = t >> 2;
  const int skc = (((t & 3) ^ ((t >> 3) & 3)) * 8);   // swizzled source chunk
  const int qx8 = (quad ^ ((l16 >> 1) & 3)) * 8;      // swizzled read chunk

  floatx4 acc[2][4] = {};

  const int ra  = min(row0 + srow, M - 1);
  const int rb0 = col0 + srow;
  const int rb1 = col0 + 64 + srow;

  const ushort_t* gAh = Ahi + (size_t)ra * K + skc;
  const ushort_t* gAl = Alo + (size_t)ra * K + skc;
  const ushort_t* gB0h = Bhi + (size_t)rb0 * K + skc;
  const ushort_t* gB1h = Bhi + (size_t)rb1 * K + skc;
  const ushort_t* gB0l = Blo + (size_t)rb0 * K + skc;
  const ushort_t* gB1l = Blo + (size_t)rb1 * K + skc;

#define STAGE(c, kt) {                                  \
    gll16(gAh + (kt), &sAh[c][wave * 512]);             \
    gll16(gAl + (kt), &sAl[c][wave * 512]);             \
    gll16(gB0h + (kt), &sBh[c][wave * 512]);            \
    gll16(gB1h + (kt), &sBh[c][2048 + wave * 512]);     \
    gll16(gB0l + (kt), &sBl[c][wave * 512]);            \
    gll16(gB1l + (kt), &sBl[c][2048 + wave * 512]); }

  const int nk = K >> 5;
  STAGE(0, 0)
  for (int it = 0; it < nk; ++it) {
    const int c = it & 1;
    if (it + 1 < nk) {
      STAGE(c ^ 1, (it + 1) * 32)
      asm volatile("s_waitcnt vmcnt(6)\n\ts_barrier" ::: "memory");
    } else {
      asm volatile("s_waitcnt vmcnt(0)\n\ts_barrier" ::: "memory");
    }

    bf16x8 ah[2], al[2], bh[4], bl[4];
#pragma unroll
    for (int i = 0; i < 2; ++i) {
      int off = (wm * 32 + i * 16 + l16) * 32 + qx8;
      ah[i] = *(const bf16x8*)&sAh[c][off];
      al[i] = *(const bf16x8*)&sAl[c][off];
    }
#pragma unroll
    for (int j = 0; j < 4; ++j) {
      int off = (wn * 64 + j * 16 + l16) * 32 + qx8;
      bh[j] = *(const bf16x8*)&sBh[c][off];
      bl[j] = *(const bf16x8*)&sBl[c][off];
    }
#pragma unroll
    for (int i = 0; i < 2; ++i)
#pragma unroll
      for (int j = 0; j < 4; ++j) {
        acc[i][j] = __builtin_amdgcn_mfma_f32_16x16x32_bf16(ah[i], bh[j], acc[i][j], 0, 0, 0);
        acc[i][j] = __builtin_amdgcn_mfma_f32_16x16x32_bf16(ah[i], bl[j], acc[i][j], 0, 0, 0);
        acc[i][j] = __builtin_amdgcn_mfma_f32_16x16x32_bf16(al[i], bh[j], acc[i][j], 0, 0, 0);
      }
    asm volatile("s_barrier" ::: "memory");
  }
#undef STAGE

#pragma unroll
  for (int i = 0; i < 2; ++i) {
#pragma unroll
    for (int j = 0; j < 4; ++j) {
      int gc = col0 + wn * 64 + j * 16 + l16;
#pragma unroll
      for (int reg = 0; reg < 4; ++reg) {
        int gr = row0 + wm * 32 + i * 16 + quad * 4 + reg;
        if (gr >= M) continue;
        float v = acc[i][j][reg];
        size_t o = (size_t)gr * N + gc;
        if (EPI) {
          v += bias[gc];
          v = fmaxf(v, 0.0f);
          v *= drop_scale((unsigned)gr * (unsigned)N + (unsigned)gc, dk0, dk1);
          ushort_t h = f2bf(v);
          Chi[o] = h;
          Clo[o] = f2bf(v - bf2f(h));
        } else {
          Cf[o] = v * dscale[gr];  // row-prescale by dinv for gather2
        }
      }
    }
  }
}

extern "C" void kernel_launch(void* const* d_in, const int* in_sizes, int n_in,
                              void* d_out, int out_size, void* d_ws, size_t ws_size,
                              hipStream_t stream) {
  const float* x  = (const float*)d_in[0];
  const void*  ei = d_in[1];
  const float* W1 = (const float*)d_in[2];
  const float* b1 = (const float*)d_in[3];
  const float* W2 = (const float*)d_in[4];
  const float* b2 = (const float*)d_in[5];
  float* out = (float*)d_out;

  const int N = in_sizes[0] / C_IN;   // 10000
  const int E = in_sizes[1] / 2;      // 160000
  const int NB = (N + 255) / 256;     // 40

  unsigned a0 = 0u, a1 = 0u, b0 = 0u, b1k = 1u;
  tf_rounds(a0, a1, 0u, 42u);   // dk1
  tf_rounds(b0, b1k, 0u, 42u);  // dk2

  uintptr_t base = (uintptr_t)d_ws;
  unsigned*  flag   = (unsigned*)base;
  int*       cnt    = (int*)(base + 16 * 1024);
  int*       roff   = (int*)(base + 64 * 1024);
  int*       cursor = (int*)(base + 128 * 1024);
  float*     dinv   = (float*)(base + 192 * 1024);
  int*       csr    = (int*)(base + 2u * 1024 * 1024);
  ushort_t*  Ahi    = (ushort_t*)(base + 4u  * 1024 * 1024);
  ushort_t*  Alo    = (ushort_t*)(base + 10u * 1024 * 1024);
  ushort_t*  H1hi   = (ushort_t*)(base + 16u * 1024 * 1024);
  ushort_t*  H1lo   = (ushort_t*)(base + 27u * 1024 * 1024);
  float*     hw2    = (float*)(base + 38u * 1024 * 1024);
  ushort_t*  W1thi  = (ushort_t*)(base + 49u * 1024 * 1024);
  ushort_t*  W1tlo  = (ushort_t*)(base + 49u * 1024 * 1024 + 512 * 1024);
  ushort_t*  W2thi  = (ushort_t*)(base + 50u * 1024 * 1024);
  ushort_t*  W2tlo  = (ushort_t*)(base + 50u * 1024 * 1024 + 512 * 1024);

  dim3 b256(256);
  const int WCB = (C_IN * C_HID + C_HID * C_OUT + 255) / 256;

  // 1. fused setup: zero cnt | detect | weight convert
  k_setup<<<dim3(NB + 1 + WCB), b256, 0, stream>>>((const unsigned*)ei, flag, cnt,
                                                   N, NB, W1, W2,
                                                   W1thi, W1tlo, W2thi, W2tlo);
  // 2. degree histogram
  k_hist<<<dim3((E + 255) / 256), b256, 0, stream>>>(ei, flag, cnt, E);
  // 3. single-block scan
  k_scan<<<dim3(1), dim3(1024), 0, stream>>>(cnt, roff, cursor, dinv, N, E);
  // 4. CSR scatter
  k_scatter<<<dim3((E + 255) / 256), b256, 0, stream>>>(ei, flag, cursor, csr, E);
  // 5. layer-1 aggregate (full-TLP gather) -> bf16 split A
  k_gather4<0, 0><<<dim3(N / 4), b256, 0, stream>>>(roff, csr, dinv, x, nullptr,
                                                    Ahi, Alo, 0u, 0u);
  // 6. h1 = drop(relu(agg @ W1 + b1)) -> bf16 split   [grid 4 x 157]
  k_gemm3<1><<<dim3(C_HID / 128, (N + 63) / 64), b256, 0, stream>>>(
      Ahi, Alo, W1thi, W1tlo, b1, nullptr, H1hi, H1lo, nullptr,
      N, C_HID, C_IN, a0, a1);
  // 7. hw2' = dinv * (h1 @ W2)  (fp32, row-prescaled)  [grid 2 x 157]
  k_gemm3<0><<<dim3(C_OUT / 128, (N + 63) / 64), b256, 0, stream>>>(
      H1hi, H1lo, W2thi, W2tlo, nullptr, dinv, nullptr, nullptr, hw2,
      N, C_OUT, C_HID, 0u, 0u);
  // 8. out = drop(relu(dd * (sum hw2'[nbrs] + hw2'[self]) + b2))
  k_gather4<1, 1><<<dim3(N / 4), b256, 0, stream>>>(roff, csr, dinv, hw2, b2,
                                                    out, nullptr, b0, b1k);
}

// Round 10
// 198.504 us; speedup vs baseline: 1.1455x; 1.0351x over previous
//
#include <hip/hip_runtime.h>
#include <stdint.h>

// GCN 2-layer: out = drop(relu(A_hat * (drop(relu((A_hat*X)*W1+b1)) * W2) + b2))
// v11 = v4 verbatim (session best, 198.2us measured). v10's preproc recombination
//       (-1 launch) measured +7us -> reverted. Fused-GEMM line (v6-v9) abandoned:
//       52/56/79us vs 2x21us standalone. Gathers at L3-BW roofline (~7TB/s eff).

#define C_IN 256
#define C_HID 512
#define C_OUT 256

typedef unsigned short ushort_t;
typedef __bf16 bf16x8 __attribute__((ext_vector_type(8)));
typedef float floatx4 __attribute__((ext_vector_type(4)));

typedef __attribute__((address_space(1))) const void g1_void;
typedef __attribute__((address_space(3))) void l3_void;

__device__ __forceinline__ void gll16(const ushort_t* g, ushort_t* l) {
  __builtin_amdgcn_global_load_lds((g1_void*)g, (l3_void*)l, 16, 0, 0);
}

// ---------------- Threefry-2x32 (matches JAX) ----------------
__host__ __device__ __forceinline__ void tf_rounds(unsigned& x0, unsigned& x1,
                                                   unsigned k0, unsigned k1) {
  unsigned k2 = k0 ^ k1 ^ 0x1BD11BDAu;
#define ROT(r) { x0 += x1; x1 = (x1 << r) | (x1 >> (32 - r)); x1 ^= x0; }
  x0 += k0; x1 += k1;
  ROT(13) ROT(15) ROT(26) ROT(6)
  x0 += k1; x1 += k2 + 1u;
  ROT(17) ROT(29) ROT(16) ROT(24)
  x0 += k2; x1 += k0 + 2u;
  ROT(13) ROT(15) ROT(26) ROT(6)
  x0 += k0; x1 += k1 + 3u;
  ROT(17) ROT(29) ROT(16) ROT(24)
  x0 += k1; x1 += k2 + 4u;
  ROT(13) ROT(15) ROT(26) ROT(6)
  x0 += k2; x1 += k0 + 5u;
#undef ROT
}

__device__ __forceinline__ float drop_scale(unsigned j, unsigned k0, unsigned k1) {
  unsigned x0 = 0u, x1 = j;
  tf_rounds(x0, x1, k0, k1);
  unsigned bits = x0 ^ x1;
  float u = __uint_as_float((bits >> 9) | 0x3f800000u) - 1.0f;
  return (u < 0.5f) ? 2.0f : 0.0f;
}

// bf16 helpers (RNE)
__device__ __forceinline__ ushort_t f2bf(float f) {
  unsigned u = __float_as_uint(f);
  unsigned r = (u + 0x7fffu + ((u >> 16) & 1u)) >> 16;
  return (ushort_t)r;
}
__device__ __forceinline__ float bf2f(ushort_t h) {
  return __uint_as_float(((unsigned)h) << 16);
}

// ---------------- fused setup: zero cnt | detect dtype | weight convert ----
// blocks [0,NB): zero cnt ; block NB: detect ; blocks (NB, NB+1024]: wconv
__global__ __launch_bounds__(256) void k_setup(const unsigned* __restrict__ raw,
                                               unsigned* __restrict__ flag,
                                               int* __restrict__ cnt, int N, int NB,
                                               const float* __restrict__ W1,
                                               const float* __restrict__ W2,
                                               ushort_t* __restrict__ h1,
                                               ushort_t* __restrict__ l1,
                                               ushort_t* __restrict__ h2,
                                               ushort_t* __restrict__ l2) {
  int b = blockIdx.x, t = threadIdx.x;
  if (b < NB) {
    int i = b * 256 + t;
    if (i < N) cnt[i] = 0;
    return;
  }
  if (b == NB) {
    __shared__ unsigned sh[256];
    unsigned acc = 0;
    for (int i = 1 + 2 * t; i < 8192; i += 512) acc |= raw[i];
    sh[t] = acc;
    __syncthreads();
    for (int s = 128; s > 0; s >>= 1) {
      if (t < s) sh[t] |= sh[t + s];
      __syncthreads();
    }
    if (t == 0) *flag = (sh[0] == 0u) ? 1u : 0u;  // 1 => int64
    return;
  }
  int idx = (b - NB - 1) * 256 + t;
  const int S1 = C_IN * C_HID;
  if (idx >= S1 + C_HID * C_OUT) return;
  const float* W; ushort_t *hi, *lo; int K, Nn, li;
  if (idx < S1) { W = W1; hi = h1; lo = l1; K = C_IN; Nn = C_HID; li = idx; }
  else { W = W2; hi = h2; lo = l2; K = C_HID; Nn = C_OUT; li = idx - S1; }
  int k = li / Nn, n = li - k * Nn;
  float v = W[li];
  ushort_t h = f2bf(v);
  hi[(size_t)n * K + k] = h;
  lo[(size_t)n * K + k] = f2bf(v - bf2f(h));
}

// convert + fused dst-degree histogram (cnt must be pre-zeroed)
__global__ __launch_bounds__(256) void k_convert(const void* __restrict__ raw,
                                                 const unsigned* __restrict__ flag,
                                                 int* __restrict__ eic,
                                                 int* __restrict__ cnt,
                                                 int E) {
  int i = blockIdx.x * 256 + threadIdx.x;
  if (i >= 2 * E) return;
  int v;
  if (*flag) v = (int)((const long long*)raw)[i];
  else       v = ((const int*)raw)[i];
  eic[i] = v;
  if (i >= E) atomicAdd(&cnt[v], 1);  // dst half -> in-degree
}

// ---------------- scan: A (block sums), C (per-block prefix of bsum + emit) -
__global__ __launch_bounds__(256) void k_scan_a(const int* __restrict__ cnt,
                                                int* __restrict__ bsum, int n) {
  __shared__ int sh[256];
  int i = blockIdx.x * 256 + threadIdx.x;
  sh[threadIdx.x] = (i < n) ? cnt[i] : 0;
  __syncthreads();
  for (int s = 128; s > 0; s >>= 1) {
    if ((int)threadIdx.x < s) sh[threadIdx.x] += sh[threadIdx.x + s];
    __syncthreads();
  }
  if (threadIdx.x == 0) bsum[blockIdx.x] = sh[0];
}

// phase C: wave0 reduces bsum[0..blockIdx) itself; in-block scan + fused dinv.
__global__ __launch_bounds__(256) void k_scan_c(const int* __restrict__ cnt,
                                                const int* __restrict__ bsum,
                                                int* __restrict__ roff,
                                                int* __restrict__ cursor,
                                                float* __restrict__ dinv,
                                                int n, int NB, int E) {
  __shared__ int sh[256];
  __shared__ int spre;
  int t = threadIdx.x;
  if (t < 64) {
    int v = (t < (int)blockIdx.x && t < NB) ? bsum[t] : 0;
    for (int s = 32; s > 0; s >>= 1) v += __shfl_down(v, s);
    if (t == 0) spre = v;
  }
  int i = blockIdx.x * 256 + t;
  int v = (i < n) ? cnt[i] : 0;
  sh[t] = v;
  __syncthreads();
  for (int s = 1; s < 256; s <<= 1) {
    int tv = (t >= s) ? sh[t - s] : 0;
    __syncthreads();
    sh[t] += tv;
    __syncthreads();
  }
  if (i < n) {
    int excl = spre + sh[t] - v;
    roff[i] = excl;
    cursor[i] = excl;
    dinv[i] = rsqrtf((float)(v + 1));  // +1 self-loop
  }
  if (blockIdx.x == 0 && t == 0) roff[n] = E;
}

__global__ __launch_bounds__(256) void k_scatter(const int* __restrict__ eic,
                                                 int* __restrict__ cursor,
                                                 int* __restrict__ csr, int E) {
  int e = blockIdx.x * 256 + threadIdx.x;
  if (e >= E) return;
  int s = eic[e], d = eic[E + e];
  int slot = atomicAdd(&cursor[d], 1);
  csr[slot] = s;
}

// ---------------- gather: 4 nodes/block, 64 lanes x float4, unroll-8 --------
template <int EPI, int PRE>
__global__ __launch_bounds__(256) void k_gather4(const int* __restrict__ roff,
                                                 const int* __restrict__ csr,
                                                 const float* __restrict__ dinv,
                                                 const float* __restrict__ x,
                                                 const float* __restrict__ bias,
                                                 void* __restrict__ o1,
                                                 void* __restrict__ o2,
                                                 unsigned dk0, unsigned dk1) {
  int g = threadIdx.x >> 6;
  int tg = threadIdx.x & 63;
  int node = blockIdx.x * 4 + g;
  float dd = dinv[node];
  const float4* xr = (const float4*)x;
  float4 v = xr[(size_t)node * 64 + tg];
  float4 acc;
  if (PRE) acc = v;
  else acc = make_float4(dd * v.x, dd * v.y, dd * v.z, dd * v.w);
  int p = roff[node], end = roff[node + 1];
  for (; p + 8 <= end; p += 8) {
    int s[8];
#pragma unroll
    for (int q = 0; q < 8; ++q) s[q] = csr[p + q];
    float4 r[8];
#pragma unroll
    for (int q = 0; q < 8; ++q) r[q] = xr[(size_t)s[q] * 64 + tg];
    if (PRE) {
#pragma unroll
      for (int q = 0; q < 8; ++q) {
        acc.x += r[q].x; acc.y += r[q].y; acc.z += r[q].z; acc.w += r[q].w;
      }
    } else {
      float w[8];
#pragma unroll
      for (int q = 0; q < 8; ++q) w[q] = dinv[s[q]];
#pragma unroll
      for (int q = 0; q < 8; ++q) {
        acc.x += w[q] * r[q].x; acc.y += w[q] * r[q].y;
        acc.z += w[q] * r[q].z; acc.w += w[q] * r[q].w;
      }
    }
  }
  for (; p + 4 <= end; p += 4) {
    int s0 = csr[p], s1 = csr[p + 1], s2 = csr[p + 2], s3 = csr[p + 3];
    float4 a = xr[(size_t)s0 * 64 + tg];
    float4 b = xr[(size_t)s1 * 64 + tg];
    float4 c = xr[(size_t)s2 * 64 + tg];
    float4 d = xr[(size_t)s3 * 64 + tg];
    if (PRE) {
      acc.x += a.x + b.x + c.x + d.x;
      acc.y += a.y + b.y + c.y + d.y;
      acc.z += a.z + b.z + c.z + d.z;
      acc.w += a.w + b.w + c.w + d.w;
    } else {
      float w0 = dinv[s0], w1 = dinv[s1], w2 = dinv[s2], w3 = dinv[s3];
      acc.x += w0 * a.x + w1 * b.x + w2 * c.x + w3 * d.x;
      acc.y += w0 * a.y + w1 * b.y + w2 * c.y + w3 * d.y;
      acc.z += w0 * a.z + w1 * b.z + w2 * c.z + w3 * d.z;
      acc.w += w0 * a.w + w1 * b.w + w2 * c.w + w3 * d.w;
    }
  }
  for (; p < end; ++p) {
    int s0 = csr[p];
    float4 a = xr[(size_t)s0 * 64 + tg];
    if (PRE) {
      acc.x += a.x; acc.y += a.y; acc.z += a.z; acc.w += a.w;
    } else {
      float w0 = dinv[s0];
      acc.x += w0 * a.x; acc.y += w0 * a.y; acc.z += w0 * a.z; acc.w += w0 * a.w;
    }
  }
  acc.x *= dd; acc.y *= dd; acc.z *= dd; acc.w *= dd;
  if (EPI) {
    float4 bb = ((const float4*)bias)[tg];
    acc.x = fmaxf(acc.x + bb.x, 0.0f);
    acc.y = fmaxf(acc.y + bb.y, 0.0f);
    acc.z = fmaxf(acc.z + bb.z, 0.0f);
    acc.w = fmaxf(acc.w + bb.w, 0.0f);
    unsigned jb = (unsigned)node * 256u + (unsigned)tg * 4u;
    acc.x *= drop_scale(jb + 0u, dk0, dk1);
    acc.y *= drop_scale(jb + 1u, dk0, dk1);
    acc.z *= drop_scale(jb + 2u, dk0, dk1);
    acc.w *= drop_scale(jb + 3u, dk0, dk1);
    ((float4*)o1)[(size_t)node * 64 + tg] = acc;
  } else {
    ushort_t h0 = f2bf(acc.x), h1 = f2bf(acc.y), h2 = f2bf(acc.z), h3 = f2bf(acc.w);
    ushort4 hv = make_ushort4(h0, h1, h2, h3);
    ushort4 lv = make_ushort4(f2bf(acc.x - bf2f(h0)), f2bf(acc.y - bf2f(h1)),
                              f2bf(acc.z - bf2f(h2)), f2bf(acc.w - bf2f(h3)));
    ((ushort4*)o1)[(size_t)node * 64 + tg] = hv;
    ((ushort4*)o2)[(size_t)node * 64 + tg] = lv;
  }
}

// ---------------- bf16x3 MFMA GEMM: 64x128 tile, dbuf gll16 + counted vmcnt -
// LDS chunk-XOR swizzle: global source pre-swizzled (skc), reads XOR chunk (qx8).
template <int EPI>
__global__ __launch_bounds__(256) void k_gemm3(
    const ushort_t* __restrict__ Ahi, const ushort_t* __restrict__ Alo,
    const ushort_t* __restrict__ Bhi, const ushort_t* __restrict__ Blo,
    const float* __restrict__ bias, const float* __restrict__ dscale,
    ushort_t* __restrict__ Chi, ushort_t* __restrict__ Clo,
    float* __restrict__ Cf,
    int M, int N, int K, unsigned dk0, unsigned dk1) {
  __shared__ ushort_t sAh[2][64 * 32], sAl[2][64 * 32];
  __shared__ ushort_t sBh[2][128 * 32], sBl[2][128 * 32];
  const int t = threadIdx.x;
  const int lane = t & 63, wave = t >> 6;
  const int wm = wave & 1, wn = wave >> 1;
  const int quad = lane >> 4, l16 = lane & 15;
  const int row0 = blockIdx.y * 64, col0 = blockIdx.x * 128;
  const int srow = t >> 2;
  const int skc = (((t & 3) ^ ((t >> 3) & 3)) * 8);   // swizzled source chunk
  const int qx8 = (quad ^ ((l16 >> 1) & 3)) * 8;      // swizzled read chunk

  floatx4 acc[2][4] = {};

  const int ra  = min(row0 + srow, M - 1);
  const int rb0 = col0 + srow;
  const int rb1 = col0 + 64 + srow;

  const ushort_t* gAh = Ahi + (size_t)ra * K + skc;
  const ushort_t* gAl = Alo + (size_t)ra * K + skc;
  const ushort_t* gB0h = Bhi + (size_t)rb0 * K + skc;
  const ushort_t* gB1h = Bhi + (size_t)rb1 * K + skc;
  const ushort_t* gB0l = Blo + (size_t)rb0 * K + skc;
  const ushort_t* gB1l = Blo + (size_t)rb1 * K + skc;

#define STAGE(c, kt) {                                  \
    gll16(gAh + (kt), &sAh[c][wave * 512]);             \
    gll16(gAl + (kt), &sAl[c][wave * 512]);             \
    gll16(gB0h + (kt), &sBh[c][wave * 512]);            \
    gll16(gB1h + (kt), &sBh[c][2048 + wave * 512]);     \
    gll16(gB0l + (kt), &sBl[c][wave * 512]);            \
    gll16(gB1l + (kt), &sBl[c][2048 + wave * 512]); }

  const int nk = K >> 5;
  STAGE(0, 0)
  for (int it = 0; it < nk; ++it) {
    const int c = it & 1;
    if (it + 1 < nk) {
      STAGE(c ^ 1, (it + 1) * 32)
      asm volatile("s_waitcnt vmcnt(6)\n\ts_barrier" ::: "memory");
    } else {
      asm volatile("s_waitcnt vmcnt(0)\n\ts_barrier" ::: "memory");
    }

    bf16x8 ah[2], al[2], bh[4], bl[4];
#pragma unroll
    for (int i = 0; i < 2; ++i) {
      int off = (wm * 32 + i * 16 + l16) * 32 + qx8;
      ah[i] = *(const bf16x8*)&sAh[c][off];
      al[i] = *(const bf16x8*)&sAl[c][off];
    }
#pragma unroll
    for (int j = 0; j < 4; ++j) {
      int off = (wn * 64 + j * 16 + l16) * 32 + qx8;
      bh[j] = *(const bf16x8*)&sBh[c][off];
      bl[j] = *(const bf16x8*)&sBl[c][off];
    }
#pragma unroll
    for (int i = 0; i < 2; ++i)
#pragma unroll
      for (int j = 0; j < 4; ++j) {
        acc[i][j] = __builtin_amdgcn_mfma_f32_16x16x32_bf16(ah[i], bh[j], acc[i][j], 0, 0, 0);
        acc[i][j] = __builtin_amdgcn_mfma_f32_16x16x32_bf16(ah[i], bl[j], acc[i][j], 0, 0, 0);
        acc[i][j] = __builtin_amdgcn_mfma_f32_16x16x32_bf16(al[i], bh[j], acc[i][j], 0, 0, 0);
      }
    asm volatile("s_barrier" ::: "memory");  // reads done before next stage overwrites
  }
#undef STAGE

#pragma unroll
  for (int i = 0; i < 2; ++i) {
#pragma unroll
    for (int j = 0; j < 4; ++j) {
      int gc = col0 + wn * 64 + j * 16 + l16;
#pragma unroll
      for (int reg = 0; reg < 4; ++reg) {
        int gr = row0 + wm * 32 + i * 16 + quad * 4 + reg;
        if (gr >= M) continue;
        float v = acc[i][j][reg];
        size_t o = (size_t)gr * N + gc;
        if (EPI) {
          v += bias[gc];
          v = fmaxf(v, 0.0f);
          v *= drop_scale((unsigned)gr * (unsigned)N + (unsigned)gc, dk0, dk1);
          ushort_t h = f2bf(v);
          Chi[o] = h;
          Clo[o] = f2bf(v - bf2f(h));
        } else {
          Cf[o] = v * dscale[gr];  // row-prescale by dinv for gather2
        }
      }
    }
  }
}

extern "C" void kernel_launch(void* const* d_in, const int* in_sizes, int n_in,
                              void* d_out, int out_size, void* d_ws, size_t ws_size,
                              hipStream_t stream) {
  const float* x  = (const float*)d_in[0];
  const void*  ei = d_in[1];
  const float* W1 = (const float*)d_in[2];
  const float* b1 = (const float*)d_in[3];
  const float* W2 = (const float*)d_in[4];
  const float* b2 = (const float*)d_in[5];
  float* out = (float*)d_out;

  const int N = in_sizes[0] / C_IN;   // 10000
  const int E = in_sizes[1] / 2;      // 160000
  const int NB = (N + 255) / 256;     // 40

  // foldlike split(key(42)): dk_i = threefry((0,42), (0, i))
  unsigned a0 = 0u, a1 = 0u, b0 = 0u, b1k = 1u;
  tf_rounds(a0, a1, 0u, 42u);   // dk1
  tf_rounds(b0, b1k, 0u, 42u);  // dk2

  // workspace layout
  uintptr_t base = (uintptr_t)d_ws;
  unsigned*  flag   = (unsigned*)base;
  int*       bsum   = (int*)(base + 4096);
  int*       cnt    = (int*)(base + 16 * 1024);
  int*       roff   = (int*)(base + 64 * 1024);
  int*       cursor = (int*)(base + 128 * 1024);
  float*     dinv   = (float*)(base + 192 * 1024);
  int*       eic    = (int*)(base + 256 * 1024);
  int*       csr    = (int*)(base + 2u * 1024 * 1024);
  ushort_t*  Ahi    = (ushort_t*)(base + 4u  * 1024 * 1024);
  ushort_t*  Alo    = (ushort_t*)(base + 10u * 1024 * 1024);
  ushort_t*  H1hi   = (ushort_t*)(base + 16u * 1024 * 1024);
  ushort_t*  H1lo   = (ushort_t*)(base + 27u * 1024 * 1024);
  float*     hw2    = (float*)(base + 38u * 1024 * 1024);
  ushort_t*  W1thi  = (ushort_t*)(base + 49u * 1024 * 1024);
  ushort_t*  W1tlo  = (ushort_t*)(base + 49u * 1024 * 1024 + 512 * 1024);
  ushort_t*  W2thi  = (ushort_t*)(base + 50u * 1024 * 1024);
  ushort_t*  W2tlo  = (ushort_t*)(base + 50u * 1024 * 1024 + 512 * 1024);

  dim3 b256(256);
  const int WCB = (C_IN * C_HID + C_HID * C_OUT + 255) / 256;  // 1024 wconv blocks

  // 1. fused setup: zero cnt | detect | weight convert
  k_setup<<<dim3(NB + 1 + WCB), b256, 0, stream>>>((const unsigned*)ei, flag, cnt,
                                                   N, NB, W1, W2,
                                                   W1thi, W1tlo, W2thi, W2tlo);
  // 2. convert + degree histogram
  k_convert<<<dim3((2 * E + 255) / 256), b256, 0, stream>>>(ei, flag, eic, cnt, E);
  // 3-4. scan
  k_scan_a<<<dim3(NB), b256, 0, stream>>>(cnt, bsum, N);
  k_scan_c<<<dim3(NB), b256, 0, stream>>>(cnt, bsum, roff, cursor, dinv, N, NB, E);
  // 5. CSR scatter
  k_scatter<<<dim3((E + 255) / 256), b256, 0, stream>>>(eic, cursor, csr, E);
  // 6. layer 1 aggregate (gather) -> bf16 split A
  k_gather4<0, 0><<<dim3(N / 4), b256, 0, stream>>>(roff, csr, dinv, x, nullptr,
                                                    Ahi, Alo, 0u, 0u);
  // 7. h1 = drop(relu(agg @ W1 + b1)) -> bf16 split   [grid 4 x 157]
  k_gemm3<1><<<dim3(C_HID / 128, (N + 63) / 64), b256, 0, stream>>>(
      Ahi, Alo, W1thi, W1tlo, b1, nullptr, H1hi, H1lo, nullptr,
      N, C_HID, C_IN, a0, a1);
  // 8. hw2' = dinv * (h1 @ W2)  (fp32, row-prescaled)  [grid 2 x 157]
  k_gemm3<0><<<dim3(C_OUT / 128, (N + 63) / 64), b256, 0, stream>>>(
      H1hi, H1lo, W2thi, W2tlo, nullptr, dinv, nullptr, nullptr, hw2,
      N, C_OUT, C_HID, 0u, 0u);
  // 9. out = drop(relu(dd * (sum hw2'[nbrs] + hw2'[self]) + b2))
  k_gather4<1, 1><<<dim3(N / 4), b256, 0, stream>>>(roff, csr, dinv, hw2, b2,
                                                    out, nullptr, b0, b1k);
}